// Round 4
// baseline (8446.415 us; speedup 1.0000x reference)
//
#include <hip/hip_runtime.h>
#include <hip/hip_bf16.h>

#define Vv 32000
#define Tz 256
#define Hz 256

typedef __attribute__((ext_vector_type(8))) short short8;
typedef __attribute__((ext_vector_type(4))) float f32x4;

__device__ __forceinline__ float sigm(float x) { return 1.f / (1.f + __expf(-x)); }
__device__ __forceinline__ float tanh_(float x) {
    float e = __expf(2.f * x);
    return 1.f - 2.f / (e + 1.f);
}
__device__ __forceinline__ unsigned short f2bf(float x) {
    union { __hip_bfloat16 h; unsigned short u; } cv; cv.h = __float2bfloat16(x); return cv.u;
}
__device__ __forceinline__ float bf2f(unsigned short u) {
    union { unsigned u; float f; } cv; cv.u = ((unsigned)u) << 16; return cv.f;
}

// ---------- transpose+convert softmax_w [256][32000] f32 -> SWT [32000][256] bf16
__global__ __launch_bounds__(256) void k_swt(const float* __restrict__ sw,
                                             __hip_bfloat16* __restrict__ swt) {
    __shared__ float tile[64][65];
    int kt = blockIdx.x & 3, vt = blockIdx.x >> 2;
    int k0 = kt * 64, v0 = vt * 64, tid = threadIdx.x;
#pragma unroll
    for (int p = 0; p < 16; ++p) {
        int lin = p * 256 + tid;
        int kk = lin >> 6, vvi = lin & 63;
        tile[kk][vvi] = sw[(size_t)(k0 + kk) * Vv + v0 + vvi];
    }
    __syncthreads();
#pragma unroll
    for (int p = 0; p < 16; ++p) {
        int lin = p * 256 + tid;
        int vvi = lin >> 6, kk = lin & 63;
        swt[(size_t)(v0 + vvi) * 256 + k0 + kk] = __float2bfloat16(tile[kk][vvi]);
    }
}

// ---------- transpose+convert W [512][1024] f32 -> WT [1024][512] bf16 (2 layers)
__global__ __launch_bounds__(256) void k_wt(const float* __restrict__ W1,
    const float* __restrict__ W2, unsigned short* __restrict__ W1T,
    unsigned short* __restrict__ W2T) {
    __shared__ float tile[64][65];
    int bid = blockIdx.x;          // 0..255; 128 tiles per layer
    int layer = bid >> 7;
    int tl = bid & 127;            // 16 zc-tiles x 8 k-tiles
    int zc0 = (tl >> 3) * 64, k0 = (tl & 7) * 64;
    const float* W = layer ? W2 : W1;
    unsigned short* WT = layer ? W2T : W1T;
    int tid = threadIdx.x;
#pragma unroll
    for (int p = 0; p < 16; ++p) {
        int lin = p * 256 + tid;
        int kk = lin >> 6, zz = lin & 63;
        tile[kk][zz] = W[(size_t)(k0 + kk) * 1024 + zc0 + zz];
    }
    __syncthreads();
#pragma unroll
    for (int p = 0; p < 16; ++p) {
        int lin = p * 256 + tid;
        int zz = lin >> 6, kk = lin & 63;
        WT[(size_t)(zc0 + zz) * 512 + k0 + kk] = f2bf(tile[kk][zz]);
    }
}

// ---------- embedding gather -> xs_bf [T][B][256] bf16
__global__ __launch_bounds__(64) void k_embed(const int* __restrict__ inp,
    const float* __restrict__ emb, __hip_bfloat16* __restrict__ xs) {
    int row = blockIdx.x;              // t*32 + b
    int t = row >> 5, b = row & 31;
    const float* src = emb + (size_t)inp[b * Tz + t] * Hz;
    int tid = threadIdx.x;
    float4 v = *(const float4*)&src[tid * 4];
    __hip_bfloat16* dst = xs + (size_t)row * Hz + tid * 4;
    dst[0] = __float2bfloat16(v.x); dst[1] = __float2bfloat16(v.y);
    dst[2] = __float2bfloat16(v.z); dst[3] = __float2bfloat16(v.w);
}

// ---------- persistent 2-layer LSTM: 2 blocks x 1024 threads, W VGPR-resident.
// Block 0 = layer1 (producer), block 1 = layer2 (consumer, 1 step behind).
#define LSTR 520   // LDS row stride (bf16): 1040B -> 16B-slot stride 65 (odd) -> conflict-free
__global__ __launch_bounds__(1024, 4) void k_lstm2(
    const __hip_bfloat16* __restrict__ xs,        // [256][32][256]
    const unsigned short* __restrict__ W1T,       // [1024][512] bf16
    const float* __restrict__ b1v,
    const unsigned short* __restrict__ W2T,
    const float* __restrict__ b2v,
    unsigned* __restrict__ h1buf32,               // [256][32][128] u32 (bf16 pairs)
    __hip_bfloat16* __restrict__ houtB,           // [b*256+t][256]
    unsigned* __restrict__ flags)
{
    __shared__ __align__(16) unsigned short inh[32 * LSTR];  // [b][k]: k<256 = x-half, k>=256 = h-half

    int which = blockIdx.x;           // 0 = layer1, 1 = layer2
    int tid = threadIdx.x;
    int wid = tid >> 6, l = tid & 63, lr = l & 15, lk = l >> 4;

    const unsigned short* WT = which ? W2T : W1T;
    const float* bv = which ? b2v : b1v;

    // ---- load weight fragments into VGPRs (64 short8 per wave = 256 VGPR)
    short8 Wf[4][16];
#pragma unroll
    for (int g = 0; g < 4; ++g)
#pragma unroll
        for (int kf = 0; kf < 16; ++kf)
            Wf[g][kf] = *(const short8*)&WT[(size_t)(g * 256 + wid * 16 + lr) * 512 + kf * 32 + lk * 8];

    float bias[4];
#pragma unroll
    for (int g = 0; g < 4; ++g) bias[g] = bv[g * 256 + wid * 16 + lr];

    float c_[2][4] = {{0.f, 0.f, 0.f, 0.f}, {0.f, 0.f, 0.f, 0.f}};

    // zero LDS (h(-1) = 0)
    for (int u = tid; u < 32 * LSTR; u += 1024) inh[u] = 0;
    __syncthreads();

    const unsigned short* xsu = (const unsigned short*)xs;

    for (int t = 0; t < 256; ++t) {
        // ---- stage the x-half: layer1 <- xs[t]; layer2 <- h1(t) from producer
        if (!which) {
            int b = tid >> 5, k0 = (tid & 31) * 8;
            *(short8*)&inh[b * LSTR + k0] = *(const short8*)&xsu[(size_t)t * 8192 + tid * 8];
        } else {
            if (tid == 0) {
                while (__hip_atomic_load(&flags[0], __ATOMIC_ACQUIRE,
                                         __HIP_MEMORY_SCOPE_AGENT) < (unsigned)(t + 1))
                    __builtin_amdgcn_s_sleep(2);
            }
            __syncthreads();
            int b = tid >> 5, k0 = (tid & 31) * 8;
            unsigned* dst = (unsigned*)&inh[b * LSTR + k0];
            const unsigned* src = &h1buf32[(size_t)t * 4096 + tid * 4];
#pragma unroll
            for (int q = 0; q < 4; ++q)
                dst[q] = __hip_atomic_load(&src[q], __ATOMIC_RELAXED, __HIP_MEMORY_SCOPE_AGENT);
        }
        __syncthreads();   // barA: staging visible (h-half from prev epilogue also visible)

        // ---- full-K MFMA: acc[m][g][j] = z(batch = m*16+lk*4+j, zc = g*256+wid*16+lr)
        f32x4 acc[2][4];
#pragma unroll
        for (int m = 0; m < 2; ++m)
#pragma unroll
            for (int g = 0; g < 4; ++g)
                acc[m][g] = (f32x4){bias[g], bias[g], bias[g], bias[g]};
#pragma unroll
        for (int kf = 0; kf < 16; ++kf) {
            short8 a0 = *(const short8*)&inh[lr * LSTR + kf * 32 + lk * 8];
            short8 a1 = *(const short8*)&inh[(16 + lr) * LSTR + kf * 32 + lk * 8];
#pragma unroll
            for (int g = 0; g < 4; ++g) {
                acc[0][g] = __builtin_amdgcn_mfma_f32_16x16x32_bf16(a0, Wf[g][kf], acc[0][g], 0, 0, 0);
                acc[1][g] = __builtin_amdgcn_mfma_f32_16x16x32_bf16(a1, Wf[g][kf], acc[1][g], 0, 0, 0);
            }
        }

        // ---- gates in registers (c stays in VGPRs across all 256 steps)
        unsigned short hu[2][4];
#pragma unroll
        for (int m = 0; m < 2; ++m)
#pragma unroll
            for (int j = 0; j < 4; ++j) {
                float zi = acc[m][0][j], zj = acc[m][1][j];
                float zf = acc[m][2][j], zo = acc[m][3][j];
                float cn = c_[m][j] * sigm(zf + 1.f) + sigm(zi) * tanh_(zj);
                c_[m][j] = cn;
                hu[m][j] = f2bf(tanh_(cn) * sigm(zo));
            }

        __syncthreads();   // barB: all MFMA reads of h(t-1) done before overwriting

        // ---- write h(t) into the LDS h-half
#pragma unroll
        for (int m = 0; m < 2; ++m)
#pragma unroll
            for (int j = 0; j < 4; ++j)
                inh[(m * 16 + lk * 4 + j) * LSTR + 256 + wid * 16 + lr] = hu[m][j];

        if (!which) {
            // publish h1(t): pack lane pairs into u32, agent-scope relaxed atomic stores
#pragma unroll
            for (int m = 0; m < 2; ++m)
#pragma unroll
                for (int j = 0; j < 4; ++j) {
                    unsigned mine = hu[m][j];
                    unsigned other = (unsigned)__shfl_xor((int)mine, 1);
                    if ((lr & 1) == 0) {
                        int b = m * 16 + lk * 4 + j, n = wid * 16 + lr;
                        __hip_atomic_store(&h1buf32[(size_t)t * 4096 + b * 128 + (n >> 1)],
                                           mine | (other << 16),
                                           __ATOMIC_RELAXED, __HIP_MEMORY_SCOPE_AGENT);
                    }
                }
            __syncthreads();   // barC: drains every wave's publish stores (vmcnt(0))
            if (tid == 0)
                __hip_atomic_store(&flags[0], (unsigned)(t + 1),
                                   __ATOMIC_RELEASE, __HIP_MEMORY_SCOPE_AGENT);
        } else {
            // final output h2(t), batch-major rows
#pragma unroll
            for (int m = 0; m < 2; ++m)
#pragma unroll
                for (int j = 0; j < 4; ++j) {
                    int b = m * 16 + lk * 4 + j, n = wid * 16 + lr;
                    ((unsigned short*)houtB)[(size_t)(b * 256 + t) * 256 + n] = hu[m][j];
                }
            __syncthreads();   // keep h-write ordering symmetric before next stage
        }
    }
}

// ---------- logits GEMM: 128x128 tile, BK=64, XOR-swizzled LDS, streaming sum-of-exp
__global__ __launch_bounds__(256) void k_gemm(const __hip_bfloat16* __restrict__ Abf,
    const __hip_bfloat16* __restrict__ Bbf, const float* __restrict__ sb,
    float* __restrict__ row_sum)
{
    __shared__ __align__(16) unsigned short As[128 * 64];
    __shared__ __align__(16) unsigned short Bs[128 * 64];
    int tid = threadIdx.x;
    size_t r0 = (size_t)blockIdx.x * 128;
    size_t c0 = (size_t)blockIdx.y * 128;
    int l = tid & 63, w = tid >> 6, lr = l & 15, lk = l >> 4;

    f32x4 acc[2][8];
#pragma unroll
    for (int m = 0; m < 2; ++m)
#pragma unroll
        for (int f = 0; f < 8; ++f) acc[m][f] = (f32x4){0.f, 0.f, 0.f, 0.f};

    const unsigned short* A = (const unsigned short*)Abf;
    const unsigned short* B = (const unsigned short*)Bbf;

    for (int kt = 0; kt < 4; ++kt) {
#pragma unroll
        for (int i = 0; i < 4; ++i) {
            int fi = i * 256 + tid;
            int row = fi >> 3, seg = fi & 7;
            int dseg = seg ^ (row & 7);
            *(short8*)&As[row * 64 + dseg * 8] =
                *(const short8*)&A[(r0 + row) * 256 + kt * 64 + seg * 8];
            *(short8*)&Bs[row * 64 + dseg * 8] =
                *(const short8*)&B[(c0 + row) * 256 + kt * 64 + seg * 8];
        }
        __syncthreads();
#pragma unroll
        for (int ks = 0; ks < 2; ++ks) {
            short8 a[2];
#pragma unroll
            for (int m = 0; m < 2; ++m) {
                int row = w * 32 + m * 16 + lr;
                a[m] = *(const short8*)&As[row * 64 + ((ks * 4 + lk) ^ (row & 7)) * 8];
            }
#pragma unroll
            for (int f = 0; f < 8; ++f) {
                int row = f * 16 + lr;
                short8 bfr = *(const short8*)&Bs[row * 64 + ((ks * 4 + lk) ^ (row & 7)) * 8];
#pragma unroll
                for (int m = 0; m < 2; ++m)
                    acc[m][f] = __builtin_amdgcn_mfma_f32_16x16x32_bf16(a[m], bfr, acc[m][f], 0, 0, 0);
            }
        }
        __syncthreads();
    }

    float sums[2][4] = {{0.f,0.f,0.f,0.f},{0.f,0.f,0.f,0.f}};
#pragma unroll
    for (int f = 0; f < 8; ++f) {
        float sbv = sb[c0 + f * 16 + lr];
#pragma unroll
        for (int m = 0; m < 2; ++m)
#pragma unroll
            for (int j = 0; j < 4; ++j) sums[m][j] += __expf(acc[m][f][j] + sbv);
    }
#pragma unroll
    for (int msk = 1; msk <= 8; msk <<= 1)
#pragma unroll
        for (int m = 0; m < 2; ++m)
#pragma unroll
            for (int j = 0; j < 4; ++j) sums[m][j] += __shfl_xor(sums[m][j], msk);
    if (lr == 0) {
#pragma unroll
        for (int m = 0; m < 2; ++m)
#pragma unroll
            for (int j = 0; j < 4; ++j)
                atomicAdd(&row_sum[r0 + w * 32 + m * 16 + lk * 4 + j], sums[m][j]);
    }
}

// ---------- per-row loss: log(sum_exp) - target logit (bf16 h, f32 sw), reduce
__global__ __launch_bounds__(256) void k_loss(const __hip_bfloat16* __restrict__ houtB,
    const float* __restrict__ sw, const float* __restrict__ sb,
    const int* __restrict__ tgts, const float* __restrict__ row_sum,
    float* __restrict__ out)
{
    int r = blockIdx.x * 256 + threadIdx.x;
    int tg = tgts[r];
    const unsigned short* h = (const unsigned short*)houtB + (size_t)r * Hz;
    const float* wp = sw + tg;
    float acc = 0.f;
#pragma unroll 4
    for (int k8 = 0; k8 < 32; ++k8) {
        short8 v = *(const short8*)&h[k8 * 8];
#pragma unroll
        for (int e = 0; e < 8; ++e)
            acc += bf2f((unsigned short)v[e]) * wp[(size_t)(k8 * 8 + e) * Vv];
    }
    float loss = logf(row_sum[r]) - (acc + sb[tg]);
#pragma unroll
    for (int m = 1; m < 64; m <<= 1) loss += __shfl_xor(loss, m);
    __shared__ float red[4];
    int l = threadIdx.x & 63, wv = threadIdx.x >> 6;
    if (l == 0) red[wv] = loss;
    __syncthreads();
    if (threadIdx.x == 0) {
        float s = red[0] + red[1] + red[2] + red[3];
        atomicAdd(out, s * (1.f / 8192.f));
    }
}

extern "C" void kernel_launch(void* const* d_in, const int* in_sizes, int n_in,
                              void* d_out, int out_size, void* d_ws, size_t ws_size,
                              hipStream_t stream)
{
    const int*   inp = (const int*)d_in[0];
    const int*   tgt = (const int*)d_in[1];
    const float* emb = (const float*)d_in[2];
    const float* W1  = (const float*)d_in[3];
    const float* b1  = (const float*)d_in[4];
    const float* W2  = (const float*)d_in[5];
    const float* b2  = (const float*)d_in[6];
    const float* sw  = (const float*)d_in[7];
    const float* sb  = (const float*)d_in[8];
    float* out = (float*)d_out;

    char* ws = (char*)d_ws;
    size_t off = 0;
    __hip_bfloat16* SWT  = (__hip_bfloat16*)(ws + off); off += (size_t)Vv * Hz * 2;       // 16,384,000
    __hip_bfloat16* XS   = (__hip_bfloat16*)(ws + off); off += (size_t)Tz * 32 * Hz * 2;  //  4,194,304
    unsigned short* W1T  = (unsigned short*)(ws + off); off += (size_t)1024 * 512 * 2;    //  1,048,576
    unsigned short* W2T  = (unsigned short*)(ws + off); off += (size_t)1024 * 512 * 2;    //  1,048,576
    unsigned* H1buf      = (unsigned*)(ws + off);       off += (size_t)Tz * 4096 * 4;     //  4,194,304
    __hip_bfloat16* HoutB= (__hip_bfloat16*)(ws + off); off += (size_t)8192 * Hz * 2;     //  4,194,304
    float* row_sum       = (float*)(ws + off);          off += 8192 * 4;                  //     32,768
    unsigned* flags      = (unsigned*)(ws + off);       off += 64 * 4;                    //        256
    // total ~31.1 MiB

    hipMemsetAsync(row_sum, 0, 8192 * 4 + 64 * 4, stream);   // row_sum + flags
    hipMemsetAsync(out, 0, sizeof(float), stream);

    k_embed<<<8192, 64, 0, stream>>>(inp, emb, XS);
    k_wt<<<256, 256, 0, stream>>>(W1, W2, W1T, W2T);
    k_lstm2<<<2, 1024, 0, stream>>>(XS, W1T, b1, W2T, b2, H1buf, HoutB, flags);
    k_swt<<<2000, 256, 0, stream>>>(sw, SWT);
    k_gemm<<<dim3(64, 250), 256, 0, stream>>>(HoutB, SWT, sb, row_sum);
    k_loss<<<32, 256, 0, stream>>>(HoutB, sw, sb, tgt, row_sum, out);
}

// Round 5
// 2051.486 us; speedup vs baseline: 4.1172x; 4.1172x over previous
//
#include <hip/hip_runtime.h>
#include <hip/hip_bf16.h>

#define Vv 32000
#define Tz 256
#define Hz 256

typedef __attribute__((ext_vector_type(8))) short short8;
typedef __attribute__((ext_vector_type(4))) float f32x4;
typedef __attribute__((ext_vector_type(2))) unsigned int u32x2;

__device__ __forceinline__ float sigm(float x) { return 1.f / (1.f + __expf(-x)); }
__device__ __forceinline__ float tanh_(float x) {
    float e = __expf(2.f * x);
    return 1.f - 2.f / (e + 1.f);
}
__device__ __forceinline__ unsigned short f2bf(float x) {
    union { __hip_bfloat16 h; unsigned short u; } cv; cv.h = __float2bfloat16(x); return cv.u;
}
__device__ __forceinline__ float bf2f(unsigned short u) {
    union { unsigned u; float f; } cv; cv.u = ((unsigned)u) << 16; return cv.f;
}

// ---------- transpose+convert W [512][1024] f32 -> WT [4 parts][256 zcb][512 k] bf16, per layer
// zcb = g*64 + nl;  global zc = g*256 + p*64 + nl
__global__ __launch_bounds__(256) void k_wt(const float* __restrict__ W1,
    const float* __restrict__ W2, unsigned short* __restrict__ W1T,
    unsigned short* __restrict__ W2T) {
    __shared__ float tile[64][65];
    int bid = blockIdx.x;          // 0..255; 128 tiles per layer
    int layer = bid >> 7;
    int tl = bid & 127;            // 16 zc-tiles x 8 k-tiles
    int zc0 = (tl >> 3) * 64, k0 = (tl & 7) * 64;
    int g = zc0 >> 8, p_ = (zc0 >> 6) & 3;
    const float* W = layer ? W2 : W1;
    unsigned short* WT = layer ? W2T : W1T;
    int tid = threadIdx.x;
#pragma unroll
    for (int pp = 0; pp < 16; ++pp) {
        int lin = pp * 256 + tid;
        int kk = lin >> 6, zz = lin & 63;
        tile[kk][zz] = W[(size_t)(k0 + kk) * 1024 + zc0 + zz];
    }
    __syncthreads();
#pragma unroll
    for (int pp = 0; pp < 16; ++pp) {
        int lin = pp * 256 + tid;
        int zz = lin >> 6, kk = lin & 63;
        WT[(size_t)(p_ * 256 + g * 64 + zz) * 512 + k0 + kk] = f2bf(tile[kk][zz]);
    }
}

// ---------- embedding gather -> xs_bf [T][B][256] bf16
__global__ __launch_bounds__(64) void k_embed(const int* __restrict__ inp,
    const float* __restrict__ emb, __hip_bfloat16* __restrict__ xs) {
    int row = blockIdx.x;              // t*32 + b
    int t = row >> 5, b = row & 31;
    const float* src = emb + (size_t)inp[b * Tz + t] * Hz;
    int tid = threadIdx.x;
    float4 v = *(const float4*)&src[tid * 4];
    __hip_bfloat16* dst = xs + (size_t)row * Hz + tid * 4;
    dst[0] = __float2bfloat16(v.x); dst[1] = __float2bfloat16(v.y);
    dst[2] = __float2bfloat16(v.z); dst[3] = __float2bfloat16(v.w);
}

// ---------- persistent 2-layer LSTM: 8 working blocks (4/layer), W in VGPRs.
// bid%8==0 -> layer1 part p=bid/8 (XCD 0);  bid%8==1 -> layer2 part p (XCD 1);
// bid%8>=2 -> softmax_w transpose (folded k_swt).
// Protocol: block sets its flag = t+1 after its h(t) slice is globally stored.
//   L1 step t: waits all f1 >= t     (peers' h1(t-1) slices)
//   L2 step t: waits all f1 >= t+1   (h1(t))  and all f2 >= t (h2(t-1))
#define LSTR 520   // LDS row stride (bf16): 65 x 16B slots, odd -> conflict-free frag reads
__global__ __launch_bounds__(512, 2) void k_lstm3(
    const __hip_bfloat16* __restrict__ xs,        // [256][32][256]
    const unsigned short* __restrict__ W1T,       // [4][256][512]
    const float* __restrict__ b1v,
    const unsigned short* __restrict__ W2T,
    const float* __restrict__ b2v,
    unsigned short* __restrict__ h1hist,          // [256][32][256]
    unsigned short* __restrict__ h2loc,           // [2][32][256]
    unsigned short* __restrict__ houtB,           // [8192][256] (row = b*256+t)
    unsigned* __restrict__ flags,                 // f1 at [q*16], f2 at [(4+q)*16]
    const float* __restrict__ sw,
    __hip_bfloat16* __restrict__ swt)
{
    __shared__ __align__(16) unsigned short inh[32 * LSTR];  // [b][k0..511]
    __shared__ float zl[256 * 33];                           // [zcb][b], pad 33
    __shared__ float tile[64][65];                           // transpose path

    int bid = blockIdx.x;
    int role = bid & 7;
    int p = bid >> 3;          // part 0..3
    int tid = threadIdx.x;

    if (role >= 2) {
        // ---- folded softmax_w transpose: [256][32000] f32 -> [32000][256] bf16
        int q = p * 6 + (role - 2);          // 0..23
        for (int tl = q; tl < 2000; tl += 24) {
            int kt = tl & 3, vt = tl >> 2;
            int k0 = kt * 64, v0 = vt * 64;
#pragma unroll
            for (int pp = 0; pp < 8; ++pp) {
                int lin = pp * 512 + tid;
                int kk = lin >> 6, vv = lin & 63;
                tile[kk][vv] = sw[(size_t)(k0 + kk) * Vv + v0 + vv];
            }
            __syncthreads();
#pragma unroll
            for (int pp = 0; pp < 8; ++pp) {
                int lin = pp * 512 + tid;
                int vv = lin >> 6, kk = lin & 63;
                swt[(size_t)(v0 + vv) * 256 + k0 + kk] = __float2bfloat16(tile[kk][vv]);
            }
            __syncthreads();
        }
        return;
    }

    int which = role;                       // 0 = layer1, 1 = layer2
    int wv = tid >> 6, l = tid & 63, lr = l & 15, lk = l >> 4;
    const unsigned short* WT = which ? W2T : W1T;
    const float* bv = which ? b2v : b1v;
    unsigned* f1 = flags;
    unsigned* f2 = flags + 4 * 16;
    unsigned* myflag = (which ? f2 : f1) + p * 16;

    // ---- weight fragments -> VGPRs: 32 short8 = 128 VGPR/lane (whole block = 256 KB W slice)
    short8 Wf[2][16];
    int zt0 = wv * 2;
#pragma unroll
    for (int n = 0; n < 2; ++n)
#pragma unroll
        for (int kf = 0; kf < 16; ++kf)
            Wf[n][kf] = *(const short8*)&WT[((size_t)p * 256 + (zt0 + n) * 16 + lr) * 512 + kf * 32 + lk * 8];

    // ---- epilogue constants: thread -> (batch eb, nl quad enl)
    int eb = tid & 31;
    int enl = (tid >> 5) * 4;
    float bias[4][4];
#pragma unroll
    for (int g = 0; g < 4; ++g)
#pragma unroll
        for (int qq = 0; qq < 4; ++qq)
            bias[g][qq] = bv[g * 256 + p * 64 + enl + qq];
    float c_[4] = {0.f, 0.f, 0.f, 0.f};

    int sb_ = tid >> 4, sg = tid & 15;      // staging: (batch, 16B segment)

    for (int t = 0; t < 256; ++t) {
        // ---- wait for dependencies
        if (tid == 0) {
            if (!which) {
                if (t > 0)
                    for (int q = 0; q < 4; ++q)
                        while (__hip_atomic_load(&f1[q * 16], __ATOMIC_ACQUIRE,
                                                 __HIP_MEMORY_SCOPE_AGENT) < (unsigned)t)
                            __builtin_amdgcn_s_sleep(2);
            } else {
                for (int q = 0; q < 4; ++q)
                    while (__hip_atomic_load(&f1[q * 16], __ATOMIC_ACQUIRE,
                                             __HIP_MEMORY_SCOPE_AGENT) < (unsigned)(t + 1))
                        __builtin_amdgcn_s_sleep(2);
                if (t > 0)
                    for (int q = 0; q < 4; ++q)
                        while (__hip_atomic_load(&f2[q * 16], __ATOMIC_ACQUIRE,
                                                 __HIP_MEMORY_SCOPE_AGENT) < (unsigned)t)
                            __builtin_amdgcn_s_sleep(2);
            }
        }
        __syncthreads();

        // ---- stage [x ; h(t-1)] 32x512 bf16
        {
            const unsigned short* xsrc = which ? &h1hist[(size_t)t * 8192]
                                               : (const unsigned short*)xs + (size_t)t * 8192;
            *(short8*)&inh[sb_ * LSTR + sg * 8]        = *(const short8*)&xsrc[sb_ * 256 + sg * 8];
            *(short8*)&inh[sb_ * LSTR + (sg + 16) * 8] = *(const short8*)&xsrc[sb_ * 256 + (sg + 16) * 8];
            if (t == 0) {
                short8 z8 = (short8){0, 0, 0, 0, 0, 0, 0, 0};
                *(short8*)&inh[sb_ * LSTR + 256 + sg * 8] = z8;
                *(short8*)&inh[sb_ * LSTR + 256 + (sg + 16) * 8] = z8;
            } else {
                const unsigned short* hsrc = which ? &h2loc[((t - 1) & 1) * 8192]
                                                   : &h1hist[(size_t)(t - 1) * 8192];
                *(short8*)&inh[sb_ * LSTR + 256 + sg * 8]        = *(const short8*)&hsrc[sb_ * 256 + sg * 8];
                *(short8*)&inh[sb_ * LSTR + 256 + (sg + 16) * 8] = *(const short8*)&hsrc[sb_ * 256 + (sg + 16) * 8];
            }
        }
        __syncthreads();

        // ---- MFMA: acc[m][n] = z(batch m*16+lk*4+j, zcb (zt0+n)*16+lr), K=512
        f32x4 acc[2][2];
#pragma unroll
        for (int m = 0; m < 2; ++m)
#pragma unroll
            for (int n = 0; n < 2; ++n) acc[m][n] = (f32x4){0.f, 0.f, 0.f, 0.f};
#pragma unroll
        for (int kf = 0; kf < 16; ++kf) {
            short8 a0 = *(const short8*)&inh[lr * LSTR + kf * 32 + lk * 8];
            short8 a1 = *(const short8*)&inh[(16 + lr) * LSTR + kf * 32 + lk * 8];
            acc[0][0] = __builtin_amdgcn_mfma_f32_16x16x32_bf16(a0, Wf[0][kf], acc[0][0], 0, 0, 0);
            acc[1][0] = __builtin_amdgcn_mfma_f32_16x16x32_bf16(a1, Wf[0][kf], acc[1][0], 0, 0, 0);
            acc[0][1] = __builtin_amdgcn_mfma_f32_16x16x32_bf16(a0, Wf[1][kf], acc[0][1], 0, 0, 0);
            acc[1][1] = __builtin_amdgcn_mfma_f32_16x16x32_bf16(a1, Wf[1][kf], acc[1][1], 0, 0, 0);
        }

        // ---- z -> zl[zcb][b]
#pragma unroll
        for (int n = 0; n < 2; ++n) {
            int zcb = (zt0 + n) * 16 + lr;
#pragma unroll
            for (int m = 0; m < 2; ++m)
#pragma unroll
                for (int j = 0; j < 4; ++j)
                    zl[zcb * 33 + m * 16 + lk * 4 + j] = acc[m][n][j];
        }
        __syncthreads();

        // ---- epilogue: thread (eb, enl..enl+3); c in VGPR
        {
            unsigned hp[2];
            unsigned short hu[4];
#pragma unroll
            for (int qq = 0; qq < 4; ++qq) {
                int nl = enl + qq;
                float zi = zl[(0 * 64 + nl) * 33 + eb] + bias[0][qq];
                float zj = zl[(1 * 64 + nl) * 33 + eb] + bias[1][qq];
                float zf = zl[(2 * 64 + nl) * 33 + eb] + bias[2][qq];
                float zo = zl[(3 * 64 + nl) * 33 + eb] + bias[3][qq];
                float cn = c_[qq] * sigm(zf + 1.f) + sigm(zi) * tanh_(zj);
                c_[qq] = cn;
                hu[qq] = f2bf(tanh_(cn) * sigm(zo));
            }
            hp[0] = (unsigned)hu[0] | ((unsigned)hu[1] << 16);
            hp[1] = (unsigned)hu[2] | ((unsigned)hu[3] << 16);
            u32x2 pk = (u32x2){hp[0], hp[1]};
            if (!which) {
                *(u32x2*)&h1hist[(size_t)t * 8192 + eb * 256 + p * 64 + enl] = pk;
            } else {
                *(u32x2*)&h2loc[(t & 1) * 8192 + eb * 256 + p * 64 + enl] = pk;
                *(u32x2*)&houtB[(size_t)(eb * 256 + t) * 256 + p * 64 + enl] = pk;
            }
        }
        __syncthreads();   // drains all waves' vmcnt before flag release
        if (tid == 0)
            __hip_atomic_store(myflag, (unsigned)(t + 1), __ATOMIC_RELEASE,
                               __HIP_MEMORY_SCOPE_AGENT);
    }
}

// ---------- logits GEMM: 128x128 tile, BK=64, XOR-swizzled LDS, streaming sum-of-exp
__global__ __launch_bounds__(256) void k_gemm(const __hip_bfloat16* __restrict__ Abf,
    const __hip_bfloat16* __restrict__ Bbf, const float* __restrict__ sb,
    float* __restrict__ row_sum)
{
    __shared__ __align__(16) unsigned short As[128 * 64];
    __shared__ __align__(16) unsigned short Bs[128 * 64];
    int tid = threadIdx.x;
    size_t r0 = (size_t)blockIdx.x * 128;
    size_t c0 = (size_t)blockIdx.y * 128;
    int l = tid & 63, w = tid >> 6, lr = l & 15, lk = l >> 4;

    f32x4 acc[2][8];
#pragma unroll
    for (int m = 0; m < 2; ++m)
#pragma unroll
        for (int f = 0; f < 8; ++f) acc[m][f] = (f32x4){0.f, 0.f, 0.f, 0.f};

    const unsigned short* A = (const unsigned short*)Abf;
    const unsigned short* B = (const unsigned short*)Bbf;

    for (int kt = 0; kt < 4; ++kt) {
#pragma unroll
        for (int i = 0; i < 4; ++i) {
            int fi = i * 256 + tid;
            int row = fi >> 3, seg = fi & 7;
            int dseg = seg ^ (row & 7);
            *(short8*)&As[row * 64 + dseg * 8] =
                *(const short8*)&A[(r0 + row) * 256 + kt * 64 + seg * 8];
            *(short8*)&Bs[row * 64 + dseg * 8] =
                *(const short8*)&B[(c0 + row) * 256 + kt * 64 + seg * 8];
        }
        __syncthreads();
#pragma unroll
        for (int ks = 0; ks < 2; ++ks) {
            short8 a[2];
#pragma unroll
            for (int m = 0; m < 2; ++m) {
                int row = w * 32 + m * 16 + lr;
                a[m] = *(const short8*)&As[row * 64 + ((ks * 4 + lk) ^ (row & 7)) * 8];
            }
#pragma unroll
            for (int f = 0; f < 8; ++f) {
                int row = f * 16 + lr;
                short8 bfr = *(const short8*)&Bs[row * 64 + ((ks * 4 + lk) ^ (row & 7)) * 8];
#pragma unroll
                for (int m = 0; m < 2; ++m)
                    acc[m][f] = __builtin_amdgcn_mfma_f32_16x16x32_bf16(a[m], bfr, acc[m][f], 0, 0, 0);
            }
        }
        __syncthreads();
    }

    float sums[2][4] = {{0.f,0.f,0.f,0.f},{0.f,0.f,0.f,0.f}};
#pragma unroll
    for (int f = 0; f < 8; ++f) {
        float sbv = sb[c0 + f * 16 + lr];
#pragma unroll
        for (int m = 0; m < 2; ++m)
#pragma unroll
            for (int j = 0; j < 4; ++j) sums[m][j] += __expf(acc[m][f][j] + sbv);
    }
#pragma unroll
    for (int msk = 1; msk <= 8; msk <<= 1)
#pragma unroll
        for (int m = 0; m < 2; ++m)
#pragma unroll
            for (int j = 0; j < 4; ++j) sums[m][j] += __shfl_xor(sums[m][j], msk);
    if (lr == 0) {
#pragma unroll
        for (int m = 0; m < 2; ++m)
#pragma unroll
            for (int j = 0; j < 4; ++j)
                atomicAdd(&row_sum[r0 + w * 32 + m * 16 + lk * 4 + j], sums[m][j]);
    }
}

// ---------- per-row loss: log(sum_exp) - target logit (bf16 h, bf16 swt coalesced)
__global__ __launch_bounds__(256) void k_loss(const __hip_bfloat16* __restrict__ houtB,
    const __hip_bfloat16* __restrict__ swt, const float* __restrict__ sb,
    const int* __restrict__ tgts, const float* __restrict__ row_sum,
    float* __restrict__ out)
{
    int r = blockIdx.x * 256 + threadIdx.x;
    int tg = tgts[r];
    const unsigned short* h = (const unsigned short*)houtB + (size_t)r * Hz;
    const unsigned short* wp = (const unsigned short*)swt + (size_t)tg * Hz;
    float acc = 0.f;
#pragma unroll 4
    for (int k8 = 0; k8 < 32; ++k8) {
        short8 hv = *(const short8*)&h[k8 * 8];
        short8 wv = *(const short8*)&wp[k8 * 8];
#pragma unroll
        for (int e = 0; e < 8; ++e)
            acc += bf2f((unsigned short)hv[e]) * bf2f((unsigned short)wv[e]);
    }
    float loss = logf(row_sum[r]) - (acc + sb[tg]);
#pragma unroll
    for (int m = 1; m < 64; m <<= 1) loss += __shfl_xor(loss, m);
    __shared__ float red[4];
    int l = threadIdx.x & 63, wvv = threadIdx.x >> 6;
    if (l == 0) red[wvv] = loss;
    __syncthreads();
    if (threadIdx.x == 0) {
        float s = red[0] + red[1] + red[2] + red[3];
        atomicAdd(out, s * (1.f / 8192.f));
    }
}

extern "C" void kernel_launch(void* const* d_in, const int* in_sizes, int n_in,
                              void* d_out, int out_size, void* d_ws, size_t ws_size,
                              hipStream_t stream)
{
    const int*   inp = (const int*)d_in[0];
    const int*   tgt = (const int*)d_in[1];
    const float* emb = (const float*)d_in[2];
    const float* W1  = (const float*)d_in[3];
    const float* b1  = (const float*)d_in[4];
    const float* W2  = (const float*)d_in[5];
    const float* b2  = (const float*)d_in[6];
    const float* sw  = (const float*)d_in[7];
    const float* sb  = (const float*)d_in[8];
    float* out = (float*)d_out;

    char* ws = (char*)d_ws;
    size_t off = 0;
    __hip_bfloat16* SWT  = (__hip_bfloat16*)(ws + off); off += (size_t)Vv * Hz * 2;       // 16,384,000
    __hip_bfloat16* XS   = (__hip_bfloat16*)(ws + off); off += (size_t)Tz * 32 * Hz * 2;  //  4,194,304
    unsigned short* W1T  = (unsigned short*)(ws + off); off += (size_t)1024 * 512 * 2;    //  1,048,576
    unsigned short* W2T  = (unsigned short*)(ws + off); off += (size_t)1024 * 512 * 2;    //  1,048,576
    unsigned short* H1h  = (unsigned short*)(ws + off); off += (size_t)Tz * 8192 * 2;     //  4,194,304
    unsigned short* H2l  = (unsigned short*)(ws + off); off += (size_t)2 * 8192 * 2;      //     32,768
    unsigned short* HoutB= (unsigned short*)(ws + off); off += (size_t)8192 * Hz * 2;     //  4,194,304
    float* row_sum       = (float*)(ws + off);          off += 8192 * 4;                  //     32,768
    unsigned* flags      = (unsigned*)(ws + off);       off += 8 * 16 * 4;                //        512
    // total ~31.1 MiB

    hipMemsetAsync(row_sum, 0, 8192 * 4 + 8 * 16 * 4, stream);   // row_sum + flags
    hipMemsetAsync(out, 0, sizeof(float), stream);

    k_embed<<<8192, 64, 0, stream>>>(inp, emb, XS);
    k_wt<<<256, 256, 0, stream>>>(W1, W2, W1T, W2T);
    k_lstm3<<<32, 512, 0, stream>>>(XS, W1T, b1, W2T, b2, H1h, H2l, HoutB, flags, sw, SWT);
    k_gemm<<<dim3(64, 250), 256, 0, stream>>>((const __hip_bfloat16*)HoutB, SWT, sb, row_sum);
    k_loss<<<32, 256, 0, stream>>>((const __hip_bfloat16*)HoutB, SWT, sb, tgt, row_sum, out);
}